// Round 8
// baseline (557.310 us; speedup 1.0000x reference)
//
#include <hip/hip_runtime.h>
#include <math.h>

#define N_NODES 50000
#define N_EDGES 800000
#define HID 16

// ---------------------------------------------------------------------------
// precompute (once per call):
//   - degree: cnt[dst] += 1 for EVERY edge (mask does not apply to counts)
//   - compact ACTIVE edge indices (same region) into comp[] (lives in d_out!)
// N_EDGES = 800000 = 3125*256 exactly -> no tail.
// ---------------------------------------------------------------------------
__global__ void precompute_kernel(const int* __restrict__ src,
                                  const int* __restrict__ dst,
                                  const int* __restrict__ region,
                                  float* __restrict__ cnt,
                                  int* __restrict__ comp,
                                  int* __restrict__ counter) {
    int e = blockIdx.x * blockDim.x + threadIdx.x;
    int s = src[e];
    int d = dst[e];
    atomicAdd(cnt + d, 1.0f);

    bool active = (region[s] == region[d]);
    unsigned long long mask = __ballot(active);
    if (mask == 0ull) return;

    int lane = threadIdx.x & 63;
    int leader = __ffsll(mask) - 1;
    int base;
    if (lane == leader) base = atomicAdd(counter, __popcll(mask));
    base = __shfl(base, leader);

    if (active) {
        int offset = __popcll(mask & ((1ull << lane) - 1ull));
        comp[base + offset] = e;
    }
}

// ---------------------------------------------------------------------------
// edge message over COMPACTED edges only (grid-stride over dynamic count):
//   msg[j] = sum_c h[src][c] * relu(rel . Win[:, c*16+j] + bin); agg[dst] += msg
// ---------------------------------------------------------------------------
template <int IN_C>
__global__ void edge_msg_compact(const float* __restrict__ x,       // pos at n*16+0..1
                                 const float* __restrict__ hbase,   // stride 16
                                 const int* __restrict__ src,
                                 const int* __restrict__ dst,
                                 const int* __restrict__ comp,
                                 const int* __restrict__ counter,
                                 const float* __restrict__ Win,     // (2, IN_C*16)
                                 const float* __restrict__ bin,     // (IN_C*16)
                                 float* __restrict__ agg) {
    int n = *counter;
    for (int i = blockIdx.x * blockDim.x + threadIdx.x; i < n;
         i += gridDim.x * blockDim.x) {
        int e = comp[i];
        int s = src[e];
        int d = dst[e];
        float rx = x[d * 16 + 0] - x[s * 16 + 0];
        float ry = x[d * 16 + 1] - x[s * 16 + 1];

        const float* hs = hbase + s * 16;
        float msg[HID];
#pragma unroll
        for (int j = 0; j < HID; ++j) msg[j] = 0.0f;

#pragma unroll
        for (int c = 0; c < IN_C; ++c) {
            float hc = hs[c];
#pragma unroll
            for (int j = 0; j < HID; ++j) {
                float sp = fmaf(rx, Win[c * HID + j],
                           fmaf(ry, Win[IN_C * HID + c * HID + j], bin[c * HID + j]));
                sp = fmaxf(sp, 0.0f);
                msg[j] = fmaf(hc, sp, msg[j]);
            }
        }

        float* ag = agg + d * HID;
#pragma unroll
        for (int j = 0; j < HID; ++j) atomicAdd(ag + j, msg[j]);
    }
}

// ---------------------------------------------------------------------------
// node update: h_out = relu((agg / max(cnt,1)) @ Wout + bout); re-zeroes agg
// so the next layer needs no memset.
// ---------------------------------------------------------------------------
__global__ void node_update_kernel(float* __restrict__ agg,
                                   const float* __restrict__ cnt,
                                   const float* __restrict__ Wout,  // (16,16)
                                   const float* __restrict__ bout,  // (16)
                                   float* __restrict__ hout) {
    int n = blockIdx.x * blockDim.x + threadIdx.x;
    if (n >= N_NODES) return;
    float inv = 1.0f / fmaxf(cnt[n], 1.0f);

    float a[HID];
    float4* ap = (float4*)(agg + n * HID);
    const float4 zero4 = make_float4(0.f, 0.f, 0.f, 0.f);
#pragma unroll
    for (int q = 0; q < 4; ++q) {
        float4 v = ap[q];
        a[q * 4 + 0] = v.x * inv;
        a[q * 4 + 1] = v.y * inv;
        a[q * 4 + 2] = v.z * inv;
        a[q * 4 + 3] = v.w * inv;
        ap[q] = zero4;                      // ready for next layer
    }

    float o[HID];
#pragma unroll
    for (int j = 0; j < HID; ++j) o[j] = bout[j];
#pragma unroll
    for (int c = 0; c < HID; ++c) {
        float ac = a[c];
#pragma unroll
        for (int j = 0; j < HID; ++j) o[j] = fmaf(ac, Wout[c * HID + j], o[j]);
    }

    float4* hp = (float4*)(hout + n * HID);
#pragma unroll
    for (int q = 0; q < 4; ++q) {
        float4 v;
        v.x = fmaxf(o[q * 4 + 0], 0.0f);
        v.y = fmaxf(o[q * 4 + 1], 0.0f);
        v.z = fmaxf(o[q * 4 + 2], 0.0f);
        v.w = fmaxf(o[q * 4 + 3], 0.0f);
        hp[q] = v;
    }
}

// ---------------------------------------------------------------------------
// decoder: z=[h[src],h[dst]] -> relu(z@Wd1+b1) -> relu(@Wd2+b2) -> sigmoid(@Wd3+b3)
// Runs LAST; overwrites d_out (which held the compacted edge list).
// ---------------------------------------------------------------------------
__global__ void decoder_kernel(const float* __restrict__ h,
                               const int* __restrict__ src,
                               const int* __restrict__ dst,
                               const float* __restrict__ Wd1,  // (32,16)
                               const float* __restrict__ bd1,
                               const float* __restrict__ Wd2,  // (16,16)
                               const float* __restrict__ bd2,
                               const float* __restrict__ Wd3,  // (16,1)
                               const float* __restrict__ bd3,
                               float* __restrict__ out) {
    int e = blockIdx.x * blockDim.x + threadIdx.x;
    if (e >= N_EDGES) return;
    int s = src[e];
    int d = dst[e];

    float z[32];
    const float4* hs = (const float4*)(h + s * HID);
    const float4* hd = (const float4*)(h + d * HID);
#pragma unroll
    for (int q = 0; q < 4; ++q) {
        float4 v = hs[q];
        z[q * 4 + 0] = v.x; z[q * 4 + 1] = v.y; z[q * 4 + 2] = v.z; z[q * 4 + 3] = v.w;
    }
#pragma unroll
    for (int q = 0; q < 4; ++q) {
        float4 v = hd[q];
        z[16 + q * 4 + 0] = v.x; z[16 + q * 4 + 1] = v.y; z[16 + q * 4 + 2] = v.z; z[16 + q * 4 + 3] = v.w;
    }

    float d1[HID];
#pragma unroll
    for (int j = 0; j < HID; ++j) d1[j] = bd1[j];
#pragma unroll
    for (int c = 0; c < 32; ++c) {
        float zc = z[c];
#pragma unroll
        for (int j = 0; j < HID; ++j) d1[j] = fmaf(zc, Wd1[c * HID + j], d1[j]);
    }
#pragma unroll
    for (int j = 0; j < HID; ++j) d1[j] = fmaxf(d1[j], 0.0f);

    float d2[HID];
#pragma unroll
    for (int j = 0; j < HID; ++j) d2[j] = bd2[j];
#pragma unroll
    for (int c = 0; c < HID; ++c) {
        float dc = d1[c];
#pragma unroll
        for (int j = 0; j < HID; ++j) d2[j] = fmaf(dc, Wd2[c * HID + j], d2[j]);
    }

    float o = bd3[0];
#pragma unroll
    for (int j = 0; j < HID; ++j) o = fmaf(fmaxf(d2[j], 0.0f), Wd3[j], o);

    out[e] = 1.0f / (1.0f + __expf(-o));
}

// ---------------------------------------------------------------------------
extern "C" void kernel_launch(void* const* d_in, const int* in_sizes, int n_in,
                              void* d_out, int out_size, void* d_ws, size_t ws_size,
                              hipStream_t stream) {
    const float* x      = (const float*)d_in[0];
    const int*   edge   = (const int*)d_in[1];   // (2, E): src row then dst row
    const int*   region = (const int*)d_in[2];
    const float* W_in1  = (const float*)d_in[3];
    const float* b_in1  = (const float*)d_in[4];
    const float* W_out1 = (const float*)d_in[5];
    const float* b_out1 = (const float*)d_in[6];
    const float* W_in2  = (const float*)d_in[7];
    const float* b_in2  = (const float*)d_in[8];
    const float* W_out2 = (const float*)d_in[9];
    const float* b_out2 = (const float*)d_in[10];
    const float* W_in3  = (const float*)d_in[11];
    const float* b_in3  = (const float*)d_in[12];
    const float* W_out3 = (const float*)d_in[13];
    const float* b_out3 = (const float*)d_in[14];
    const float* Wd1    = (const float*)d_in[15];
    const float* bd1    = (const float*)d_in[16];
    const float* Wd2    = (const float*)d_in[17];
    const float* bd2    = (const float*)d_in[18];
    const float* Wd3    = (const float*)d_in[19];
    const float* bd3    = (const float*)d_in[20];
    float* out = (float*)d_out;

    const int* src = edge;
    const int* dst = edge + N_EDGES;

    // workspace layout (floats) — same 9.8 MB footprint as the passing R0 kernel:
    //   hA[800000] hB[800000] agg[800000] cnt[50000] counter[4 ints]
    // compacted edge-id list lives in d_out (800000 ints), overwritten by decoder.
    float* ws   = (float*)d_ws;
    float* hA   = ws;
    float* hB   = hA + N_NODES * HID;
    float* agg  = hB + N_NODES * HID;
    float* cnt  = agg + N_NODES * HID;
    int*   counter = (int*)(cnt + N_NODES);
    int*   comp    = (int*)d_out;

    const int BLK = 256;
    const int egrid = N_EDGES / BLK;                  // 3125, exact
    const int ngrid = (N_NODES + BLK - 1) / BLK;
    const int cgrid = 512;                            // grid-stride over compacted edges

    // zero agg + cnt + counter (contiguous)
    hipMemsetAsync(agg, 0, (size_t)(N_NODES * HID + N_NODES + 4) * sizeof(float), stream);

    precompute_kernel<<<egrid, BLK, 0, stream>>>(src, dst, region, cnt, comp, counter);

    // layer 1: h from x columns 2..15 (row stride 16)
    edge_msg_compact<14><<<cgrid, BLK, 0, stream>>>(x, x + 2, src, dst, comp, counter, W_in1, b_in1, agg);
    node_update_kernel<<<ngrid, BLK, 0, stream>>>(agg, cnt, W_out1, b_out1, hA);

    edge_msg_compact<16><<<cgrid, BLK, 0, stream>>>(x, hA, src, dst, comp, counter, W_in2, b_in2, agg);
    node_update_kernel<<<ngrid, BLK, 0, stream>>>(agg, cnt, W_out2, b_out2, hB);

    edge_msg_compact<16><<<cgrid, BLK, 0, stream>>>(x, hB, src, dst, comp, counter, W_in3, b_in3, agg);
    node_update_kernel<<<ngrid, BLK, 0, stream>>>(agg, cnt, W_out3, b_out3, hA);

    decoder_kernel<<<egrid, BLK, 0, stream>>>(hA, src, dst, Wd1, bd1, Wd2, bd2, Wd3, bd3, out);
}

// Round 9
// 448.069 us; speedup vs baseline: 1.2438x; 1.2438x over previous
//
#include <hip/hip_runtime.h>
#include <math.h>

#define N_NODES 50000
#define N_EDGES 800000
#define HID 16

// ---------------------------------------------------------------------------
// precompute (once per call):
//   - degree: cnt[dst] += 1 for EVERY edge (INTEGER atomic — native, no CAS)
//   - compact ACTIVE edge indices (same region) into comp[] (lives in d_out!)
//     one counter atomic per BLOCK (LDS-aggregated), not per wave.
// N_EDGES = 800000 = 3125*256 exactly -> no tail.
// ---------------------------------------------------------------------------
__global__ void precompute_kernel(const int* __restrict__ src,
                                  const int* __restrict__ dst,
                                  const int* __restrict__ region,
                                  int* __restrict__ cnt,
                                  int* __restrict__ comp,
                                  int* __restrict__ counter) {
    __shared__ int wbase[4];
    int e = blockIdx.x * blockDim.x + threadIdx.x;
    int s = src[e];
    int d = dst[e];
    atomicAdd(cnt + d, 1);                      // native int atomic

    bool active = (region[s] == region[d]);
    unsigned long long mask = __ballot(active);
    int wid  = threadIdx.x >> 6;                // 4 waves / 256-thread block
    int lane = threadIdx.x & 63;
    if (lane == 0) wbase[wid] = __popcll(mask);
    __syncthreads();
    if (threadIdx.x == 0) {
        int t0 = wbase[0], t1 = wbase[1], t2 = wbase[2], t3 = wbase[3];
        int tot = t0 + t1 + t2 + t3;
        int b = tot ? atomicAdd(counter, tot) : 0;
        wbase[0] = b;
        wbase[1] = b + t0;
        wbase[2] = b + t0 + t1;
        wbase[3] = b + t0 + t1 + t2;
    }
    __syncthreads();
    if (active) {
        int offset = __popcll(mask & ((1ull << lane) - 1ull));
        comp[wbase[wid] + offset] = e;
    }
}

// ---------------------------------------------------------------------------
// edge message over COMPACTED edges only (grid-stride over dynamic count):
//   msg[j] = sum_c h[src][c] * relu(rel . Win[:, c*16+j] + bin); agg[dst] += msg
// agg updates via NATIVE fp32 atomics (unsafeAtomicAdd -> global_atomic_add_f32).
// ---------------------------------------------------------------------------
template <int IN_C>
__global__ void edge_msg_compact(const float* __restrict__ x,       // pos at n*16+0..1
                                 const float* __restrict__ hbase,   // stride 16
                                 const int* __restrict__ src,
                                 const int* __restrict__ dst,
                                 const int* __restrict__ comp,
                                 const int* __restrict__ counter,
                                 const float* __restrict__ Win,     // (2, IN_C*16)
                                 const float* __restrict__ bin,     // (IN_C*16)
                                 float* __restrict__ agg) {
    int n = *counter;
    for (int i = blockIdx.x * blockDim.x + threadIdx.x; i < n;
         i += gridDim.x * blockDim.x) {
        int e = comp[i];
        int s = src[e];
        int d = dst[e];
        float rx = x[d * 16 + 0] - x[s * 16 + 0];
        float ry = x[d * 16 + 1] - x[s * 16 + 1];

        const float* hs = hbase + s * 16;
        float msg[HID];
#pragma unroll
        for (int j = 0; j < HID; ++j) msg[j] = 0.0f;

#pragma unroll
        for (int c = 0; c < IN_C; ++c) {
            float hc = hs[c];
#pragma unroll
            for (int j = 0; j < HID; ++j) {
                float sp = fmaf(rx, Win[c * HID + j],
                           fmaf(ry, Win[IN_C * HID + c * HID + j], bin[c * HID + j]));
                sp = fmaxf(sp, 0.0f);
                msg[j] = fmaf(hc, sp, msg[j]);
            }
        }

        float* ag = agg + d * HID;
#pragma unroll
        for (int j = 0; j < HID; ++j) unsafeAtomicAdd(ag + j, msg[j]);
    }
}

// ---------------------------------------------------------------------------
// node update: h_out = relu((agg / max(cnt,1)) @ Wout + bout); re-zeroes agg
// so the next layer needs no memset. cnt is int now.
// ---------------------------------------------------------------------------
__global__ void node_update_kernel(float* __restrict__ agg,
                                   const int* __restrict__ cnt,
                                   const float* __restrict__ Wout,  // (16,16)
                                   const float* __restrict__ bout,  // (16)
                                   float* __restrict__ hout) {
    int n = blockIdx.x * blockDim.x + threadIdx.x;
    if (n >= N_NODES) return;
    float inv = 1.0f / fmaxf((float)cnt[n], 1.0f);

    float a[HID];
    float4* ap = (float4*)(agg + n * HID);
    const float4 zero4 = make_float4(0.f, 0.f, 0.f, 0.f);
#pragma unroll
    for (int q = 0; q < 4; ++q) {
        float4 v = ap[q];
        a[q * 4 + 0] = v.x * inv;
        a[q * 4 + 1] = v.y * inv;
        a[q * 4 + 2] = v.z * inv;
        a[q * 4 + 3] = v.w * inv;
        ap[q] = zero4;                      // ready for next layer
    }

    float o[HID];
#pragma unroll
    for (int j = 0; j < HID; ++j) o[j] = bout[j];
#pragma unroll
    for (int c = 0; c < HID; ++c) {
        float ac = a[c];
#pragma unroll
        for (int j = 0; j < HID; ++j) o[j] = fmaf(ac, Wout[c * HID + j], o[j]);
    }

    float4* hp = (float4*)(hout + n * HID);
#pragma unroll
    for (int q = 0; q < 4; ++q) {
        float4 v;
        v.x = fmaxf(o[q * 4 + 0], 0.0f);
        v.y = fmaxf(o[q * 4 + 1], 0.0f);
        v.z = fmaxf(o[q * 4 + 2], 0.0f);
        v.w = fmaxf(o[q * 4 + 3], 0.0f);
        hp[q] = v;
    }
}

// ---------------------------------------------------------------------------
// decoder: z=[h[src],h[dst]] -> relu(z@Wd1+b1) -> relu(@Wd2+b2) -> sigmoid(@Wd3+b3)
// Runs LAST; overwrites d_out (which held the compacted edge list).
// ---------------------------------------------------------------------------
__global__ void decoder_kernel(const float* __restrict__ h,
                               const int* __restrict__ src,
                               const int* __restrict__ dst,
                               const float* __restrict__ Wd1,  // (32,16)
                               const float* __restrict__ bd1,
                               const float* __restrict__ Wd2,  // (16,16)
                               const float* __restrict__ bd2,
                               const float* __restrict__ Wd3,  // (16,1)
                               const float* __restrict__ bd3,
                               float* __restrict__ out) {
    int e = blockIdx.x * blockDim.x + threadIdx.x;
    if (e >= N_EDGES) return;
    int s = src[e];
    int d = dst[e];

    float z[32];
    const float4* hs = (const float4*)(h + s * HID);
    const float4* hd = (const float4*)(h + d * HID);
#pragma unroll
    for (int q = 0; q < 4; ++q) {
        float4 v = hs[q];
        z[q * 4 + 0] = v.x; z[q * 4 + 1] = v.y; z[q * 4 + 2] = v.z; z[q * 4 + 3] = v.w;
    }
#pragma unroll
    for (int q = 0; q < 4; ++q) {
        float4 v = hd[q];
        z[16 + q * 4 + 0] = v.x; z[16 + q * 4 + 1] = v.y; z[16 + q * 4 + 2] = v.z; z[16 + q * 4 + 3] = v.w;
    }

    float d1[HID];
#pragma unroll
    for (int j = 0; j < HID; ++j) d1[j] = bd1[j];
#pragma unroll
    for (int c = 0; c < 32; ++c) {
        float zc = z[c];
#pragma unroll
        for (int j = 0; j < HID; ++j) d1[j] = fmaf(zc, Wd1[c * HID + j], d1[j]);
    }
#pragma unroll
    for (int j = 0; j < HID; ++j) d1[j] = fmaxf(d1[j], 0.0f);

    float d2[HID];
#pragma unroll
    for (int j = 0; j < HID; ++j) d2[j] = bd2[j];
#pragma unroll
    for (int c = 0; c < HID; ++c) {
        float dc = d1[c];
#pragma unroll
        for (int j = 0; j < HID; ++j) d2[j] = fmaf(dc, Wd2[c * HID + j], d2[j]);
    }

    float o = bd3[0];
#pragma unroll
    for (int j = 0; j < HID; ++j) o = fmaf(fmaxf(d2[j], 0.0f), Wd3[j], o);

    out[e] = 1.0f / (1.0f + __expf(-o));
}

// ---------------------------------------------------------------------------
extern "C" void kernel_launch(void* const* d_in, const int* in_sizes, int n_in,
                              void* d_out, int out_size, void* d_ws, size_t ws_size,
                              hipStream_t stream) {
    const float* x      = (const float*)d_in[0];
    const int*   edge   = (const int*)d_in[1];   // (2, E): src row then dst row
    const int*   region = (const int*)d_in[2];
    const float* W_in1  = (const float*)d_in[3];
    const float* b_in1  = (const float*)d_in[4];
    const float* W_out1 = (const float*)d_in[5];
    const float* b_out1 = (const float*)d_in[6];
    const float* W_in2  = (const float*)d_in[7];
    const float* b_in2  = (const float*)d_in[8];
    const float* W_out2 = (const float*)d_in[9];
    const float* b_out2 = (const float*)d_in[10];
    const float* W_in3  = (const float*)d_in[11];
    const float* b_in3  = (const float*)d_in[12];
    const float* W_out3 = (const float*)d_in[13];
    const float* b_out3 = (const float*)d_in[14];
    const float* Wd1    = (const float*)d_in[15];
    const float* bd1    = (const float*)d_in[16];
    const float* Wd2    = (const float*)d_in[17];
    const float* bd2    = (const float*)d_in[18];
    const float* Wd3    = (const float*)d_in[19];
    const float* bd3    = (const float*)d_in[20];
    float* out = (float*)d_out;

    const int* src = edge;
    const int* dst = edge + N_EDGES;

    // workspace layout (floats) — same 9.8 MB footprint as the passing R0 kernel:
    //   hA[800000] hB[800000] agg[800000] cnt[50000 ints] counter[4 ints]
    // compacted edge-id list lives in d_out (800000 ints), overwritten by decoder.
    float* ws   = (float*)d_ws;
    float* hA   = ws;
    float* hB   = hA + N_NODES * HID;
    float* agg  = hB + N_NODES * HID;
    int*   cnt  = (int*)(agg + N_NODES * HID);
    int*   counter = cnt + N_NODES;
    int*   comp    = (int*)d_out;

    const int BLK = 256;
    const int egrid = N_EDGES / BLK;                  // 3125, exact
    const int ngrid = (N_NODES + BLK - 1) / BLK;
    const int cgrid = 512;                            // grid-stride over compacted edges

    // zero agg + cnt + counter (contiguous)
    hipMemsetAsync(agg, 0, (size_t)(N_NODES * HID + N_NODES + 4) * sizeof(float), stream);

    precompute_kernel<<<egrid, BLK, 0, stream>>>(src, dst, region, cnt, comp, counter);

    // layer 1: h from x columns 2..15 (row stride 16)
    edge_msg_compact<14><<<cgrid, BLK, 0, stream>>>(x, x + 2, src, dst, comp, counter, W_in1, b_in1, agg);
    node_update_kernel<<<ngrid, BLK, 0, stream>>>(agg, cnt, W_out1, b_out1, hA);

    edge_msg_compact<16><<<cgrid, BLK, 0, stream>>>(x, hA, src, dst, comp, counter, W_in2, b_in2, agg);
    node_update_kernel<<<ngrid, BLK, 0, stream>>>(agg, cnt, W_out2, b_out2, hB);

    edge_msg_compact<16><<<cgrid, BLK, 0, stream>>>(x, hB, src, dst, comp, counter, W_in3, b_in3, agg);
    node_update_kernel<<<ngrid, BLK, 0, stream>>>(agg, cnt, W_out3, b_out3, hA);

    decoder_kernel<<<egrid, BLK, 0, stream>>>(hA, src, dst, Wd1, bd1, Wd2, bd2, Wd3, bd3, out);
}

// Round 10
// 312.998 us; speedup vs baseline: 1.7806x; 1.4315x over previous
//
#include <hip/hip_runtime.h>
#include <math.h>

#define N_NODES 50000
#define N_EDGES 800000
#define HID 16

// ---------------------------------------------------------------------------
// count: cnt_all[dst]++ for EVERY edge (normalization denominator);
//        cnt_act[dst]++ for same-region edges (CSR row lengths).
// Native int atomics. N_EDGES = 3125*256 exactly.
// ---------------------------------------------------------------------------
__global__ void count_kernel(const int* __restrict__ src,
                             const int* __restrict__ dst,
                             const int* __restrict__ region,
                             int* __restrict__ cnt_all,
                             int* __restrict__ cnt_act) {
    int e = blockIdx.x * blockDim.x + threadIdx.x;
    int s = src[e];
    int d = dst[e];
    atomicAdd(cnt_all + d, 1);
    if (region[s] == region[d]) atomicAdd(cnt_act + d, 1);
}

// ---------------------------------------------------------------------------
// scan: exclusive prefix sum of cnt_act (50000) -> row_ptr. One 1024-thread
// block; each thread owns ceil(50000/1024)=49 consecutive nodes.
// ---------------------------------------------------------------------------
__global__ __launch_bounds__(1024) void scan_kernel(const int* __restrict__ cnt_act,
                                                    int* __restrict__ row_ptr) {
    __shared__ int sums[1024];
    const int PER = (N_NODES + 1023) / 1024;      // 49
    int t = threadIdx.x;
    int beg = t * PER;
    int end = min(beg + PER, N_NODES);
    int s = 0;
    for (int i = beg; i < end; ++i) s += cnt_act[i];
    sums[t] = s;
    __syncthreads();
    // Hillis-Steele inclusive scan over 1024
    for (int off = 1; off < 1024; off <<= 1) {
        int v = (t >= off) ? sums[t - off] : 0;
        __syncthreads();
        sums[t] += v;
        __syncthreads();
    }
    int run = (t == 0) ? 0 : sums[t - 1];
    for (int i = beg; i < end; ++i) {
        row_ptr[i] = run;
        run += cnt_act[i];
    }
}

// ---------------------------------------------------------------------------
// fill: scatter active edge ids into CSR slots (csr_eid lives in d_out).
// ---------------------------------------------------------------------------
__global__ void fill_kernel(const int* __restrict__ src,
                            const int* __restrict__ dst,
                            const int* __restrict__ region,
                            const int* __restrict__ row_ptr,
                            int* __restrict__ cursor,
                            int* __restrict__ csr_eid) {
    int e = blockIdx.x * blockDim.x + threadIdx.x;
    int s = src[e];
    int d = dst[e];
    if (region[s] == region[d]) {
        int pos = row_ptr[d] + atomicAdd(cursor + d, 1);
        csr_eid[pos] = e;
    }
}

// ---------------------------------------------------------------------------
// fused layer (gather, NO atomics): 16 lanes per node, lane j owns channel j.
//   msg_j = sum_{e in csr[n]} sum_c h[src][c] * relu(rx*W0[c][j]+ry*W1[c][j]+b[c][j])
//   a = msg/max(cnt_all,1);  h_out[n][j] = relu(b_out[j] + sum_c a_c*Wout[c][j])
// Cross-lane a_c via __shfl within the 16-lane group (4 nodes per wave).
// grid: 50000*16/256 = 3125 blocks exactly.
// ---------------------------------------------------------------------------
template <int IN_C>
__global__ void layer_gather(const float* __restrict__ x,       // pos at n*16+0..1
                             const float* __restrict__ hbase,   // stride 16
                             const int* __restrict__ src,
                             const int* __restrict__ csr_eid,
                             const int* __restrict__ row_ptr,
                             const int* __restrict__ cnt_act,
                             const int* __restrict__ cnt_all,
                             const float* __restrict__ Win,     // (2, IN_C*16)
                             const float* __restrict__ bin,     // (IN_C*16)
                             const float* __restrict__ Wout,    // (16,16)
                             const float* __restrict__ bout,    // (16)
                             float* __restrict__ hout) {
    int t = blockIdx.x * blockDim.x + threadIdx.x;
    int n = t >> 4;                 // node
    int j = t & 15;                 // output channel of the spatial MLP

    // column j of Win / bin, hoisted (L1-broadcast across the 4 node-groups)
    float w0[IN_C], w1[IN_C], bb[IN_C];
#pragma unroll
    for (int c = 0; c < IN_C; ++c) {
        w0[c] = Win[c * HID + j];
        w1[c] = Win[IN_C * HID + c * HID + j];
        bb[c] = bin[c * HID + j];
    }

    float px = x[n * 16 + 0];
    float py = x[n * 16 + 1];

    int beg = row_ptr[n];
    int cntA = cnt_act[n];

    float msg = 0.0f;
    for (int k = 0; k < cntA; ++k) {
        int e = csr_eid[beg + k];
        int s = src[e];
        float rx = px - x[s * 16 + 0];     // rel = pos[dst]-pos[src], dst==n
        float ry = py - x[s * 16 + 1];
        const float* hs = hbase + s * 16;
        float m = 0.0f;
#pragma unroll
        for (int c = 0; c < IN_C; ++c) {
            float sp = fmaf(rx, w0[c], fmaf(ry, w1[c], bb[c]));
            sp = fmaxf(sp, 0.0f);
            m = fmaf(hs[c], sp, m);
        }
        msg += m;
    }

    float inv = 1.0f / fmaxf((float)cnt_all[n], 1.0f);
    float a = msg * inv;                    // this lane's a_j

    // out_j = bout[j] + sum_c a_c * Wout[c][j]; a_c from lane (group_base+c)
    int lane_base = (threadIdx.x & 63) & 0x30;
    float o = bout[j];
#pragma unroll
    for (int c = 0; c < HID; ++c) {
        float ac = __shfl(a, lane_base + c, 64);
        o = fmaf(ac, Wout[c * HID + j], o);
    }
    hout[n * HID + j] = fmaxf(o, 0.0f);
}

// ---------------------------------------------------------------------------
// decoder: z=[h[src],h[dst]] -> relu(z@Wd1+b1) -> relu(@Wd2+b2) -> sigmoid(@Wd3+b3)
// Runs LAST; overwrites d_out (which held csr_eid).
// ---------------------------------------------------------------------------
__global__ void decoder_kernel(const float* __restrict__ h,
                               const int* __restrict__ src,
                               const int* __restrict__ dst,
                               const float* __restrict__ Wd1,  // (32,16)
                               const float* __restrict__ bd1,
                               const float* __restrict__ Wd2,  // (16,16)
                               const float* __restrict__ bd2,
                               const float* __restrict__ Wd3,  // (16,1)
                               const float* __restrict__ bd3,
                               float* __restrict__ out) {
    int e = blockIdx.x * blockDim.x + threadIdx.x;
    if (e >= N_EDGES) return;
    int s = src[e];
    int d = dst[e];

    float z[32];
    const float4* hs = (const float4*)(h + s * HID);
    const float4* hd = (const float4*)(h + d * HID);
#pragma unroll
    for (int q = 0; q < 4; ++q) {
        float4 v = hs[q];
        z[q * 4 + 0] = v.x; z[q * 4 + 1] = v.y; z[q * 4 + 2] = v.z; z[q * 4 + 3] = v.w;
    }
#pragma unroll
    for (int q = 0; q < 4; ++q) {
        float4 v = hd[q];
        z[16 + q * 4 + 0] = v.x; z[16 + q * 4 + 1] = v.y; z[16 + q * 4 + 2] = v.z; z[16 + q * 4 + 3] = v.w;
    }

    float d1[HID];
#pragma unroll
    for (int j = 0; j < HID; ++j) d1[j] = bd1[j];
#pragma unroll
    for (int c = 0; c < 32; ++c) {
        float zc = z[c];
#pragma unroll
        for (int j = 0; j < HID; ++j) d1[j] = fmaf(zc, Wd1[c * HID + j], d1[j]);
    }
#pragma unroll
    for (int j = 0; j < HID; ++j) d1[j] = fmaxf(d1[j], 0.0f);

    float d2[HID];
#pragma unroll
    for (int j = 0; j < HID; ++j) d2[j] = bd2[j];
#pragma unroll
    for (int c = 0; c < HID; ++c) {
        float dc = d1[c];
#pragma unroll
        for (int j = 0; j < HID; ++j) d2[j] = fmaf(dc, Wd2[c * HID + j], d2[j]);
    }

    float o = bd3[0];
#pragma unroll
    for (int j = 0; j < HID; ++j) o = fmaf(fmaxf(d2[j], 0.0f), Wd3[j], o);

    out[e] = 1.0f / (1.0f + __expf(-o));
}

// ---------------------------------------------------------------------------
extern "C" void kernel_launch(void* const* d_in, const int* in_sizes, int n_in,
                              void* d_out, int out_size, void* d_ws, size_t ws_size,
                              hipStream_t stream) {
    const float* x      = (const float*)d_in[0];
    const int*   edge   = (const int*)d_in[1];   // (2, E): src row then dst row
    const int*   region = (const int*)d_in[2];
    const float* W_in1  = (const float*)d_in[3];
    const float* b_in1  = (const float*)d_in[4];
    const float* W_out1 = (const float*)d_in[5];
    const float* b_out1 = (const float*)d_in[6];
    const float* W_in2  = (const float*)d_in[7];
    const float* b_in2  = (const float*)d_in[8];
    const float* W_out2 = (const float*)d_in[9];
    const float* b_out2 = (const float*)d_in[10];
    const float* W_in3  = (const float*)d_in[11];
    const float* b_in3  = (const float*)d_in[12];
    const float* W_out3 = (const float*)d_in[13];
    const float* b_out3 = (const float*)d_in[14];
    const float* Wd1    = (const float*)d_in[15];
    const float* bd1    = (const float*)d_in[16];
    const float* Wd2    = (const float*)d_in[17];
    const float* bd2    = (const float*)d_in[18];
    const float* Wd3    = (const float*)d_in[19];
    const float* bd3    = (const float*)d_in[20];
    float* out = (float*)d_out;

    const int* src = edge;
    const int* dst = edge + N_EDGES;

    // workspace (7.2 MB, under the proven 9.8 MB footprint):
    //   hA[800000 f] hB[800000 f] cnt_all[50000 i] cnt_act[50000 i]
    //   row_ptr[50000 i] cursor[50000 i]
    // csr_eid (800000 ints worst case) lives in d_out; decoder overwrites it last.
    float* ws      = (float*)d_ws;
    float* hA      = ws;
    float* hB      = hA + N_NODES * HID;
    int*   cnt_all = (int*)(hB + N_NODES * HID);
    int*   cnt_act = cnt_all + N_NODES;
    int*   row_ptr = cnt_act + N_NODES;
    int*   cursor  = row_ptr + N_NODES;
    int*   csr_eid = (int*)d_out;

    const int BLK = 256;
    const int egrid = N_EDGES / BLK;          // 3125, exact
    const int lgrid = N_NODES * HID / BLK;    // 3125, exact (16 lanes/node)

    // zero cnt_all + cnt_act + row_ptr + cursor (contiguous 4*50000 ints)
    hipMemsetAsync(cnt_all, 0, (size_t)(4 * N_NODES) * sizeof(int), stream);

    count_kernel<<<egrid, BLK, 0, stream>>>(src, dst, region, cnt_all, cnt_act);
    scan_kernel<<<1, 1024, 0, stream>>>(cnt_act, row_ptr);
    fill_kernel<<<egrid, BLK, 0, stream>>>(src, dst, region, row_ptr, cursor, csr_eid);

    // layer 1: h from x columns 2..15 (row stride 16)
    layer_gather<14><<<lgrid, BLK, 0, stream>>>(x, x + 2, src, csr_eid, row_ptr,
                                                cnt_act, cnt_all, W_in1, b_in1,
                                                W_out1, b_out1, hA);
    layer_gather<16><<<lgrid, BLK, 0, stream>>>(x, hA, src, csr_eid, row_ptr,
                                                cnt_act, cnt_all, W_in2, b_in2,
                                                W_out2, b_out2, hB);
    layer_gather<16><<<lgrid, BLK, 0, stream>>>(x, hB, src, csr_eid, row_ptr,
                                                cnt_act, cnt_all, W_in3, b_in3,
                                                W_out3, b_out3, hA);

    decoder_kernel<<<egrid, BLK, 0, stream>>>(hA, src, dst, Wd1, bd1, Wd2, bd2, Wd3, bd3, out);
}

// Round 11
// 241.961 us; speedup vs baseline: 2.3033x; 1.2936x over previous
//
#include <hip/hip_runtime.h>
#include <math.h>

#define N_NODES 50000
#define N_EDGES 800000
#define HID 16
#define SCAN_BLOCKS ((N_NODES + 255) / 256)   // 196

// ---------------------------------------------------------------------------
// count: cnt_all[dst]++ for EVERY edge (normalization denominator);
//        cnt_act[dst]++ for same-region edges (CSR row lengths).
// Native int atomics. N_EDGES = 3125*256 exactly.
// ---------------------------------------------------------------------------
__global__ void count_kernel(const int* __restrict__ src,
                             const int* __restrict__ dst,
                             const int* __restrict__ region,
                             int* __restrict__ cnt_all,
                             int* __restrict__ cnt_act) {
    int e = blockIdx.x * blockDim.x + threadIdx.x;
    int s = src[e];
    int d = dst[e];
    atomicAdd(cnt_all + d, 1);
    if (region[s] == region[d]) atomicAdd(cnt_act + d, 1);
}

// ---------------------------------------------------------------------------
// hierarchical exclusive scan of cnt_act -> row_ptr (3 wide kernels)
// ---------------------------------------------------------------------------
__global__ void scanA_kernel(const int* __restrict__ cnt_act,
                             int* __restrict__ blockSums) {
    __shared__ int red[256];
    int i = blockIdx.x * 256 + threadIdx.x;
    red[threadIdx.x] = (i < N_NODES) ? cnt_act[i] : 0;
    __syncthreads();
    for (int off = 128; off > 0; off >>= 1) {
        if (threadIdx.x < off) red[threadIdx.x] += red[threadIdx.x + off];
        __syncthreads();
    }
    if (threadIdx.x == 0) blockSums[blockIdx.x] = red[0];
}

__global__ void scanB_kernel(const int* __restrict__ blockSums,
                             int* __restrict__ blockOff) {
    __shared__ int s[256];
    int t = threadIdx.x;
    s[t] = (t < SCAN_BLOCKS) ? blockSums[t] : 0;
    __syncthreads();
    for (int off = 1; off < 256; off <<= 1) {
        int v = (t >= off) ? s[t - off] : 0;
        __syncthreads();
        s[t] += v;
        __syncthreads();
    }
    if (t < SCAN_BLOCKS) blockOff[t] = (t == 0) ? 0 : s[t - 1];
}

__global__ void scanC_kernel(const int* __restrict__ cnt_act,
                             const int* __restrict__ blockOff,
                             int* __restrict__ row_ptr) {
    __shared__ int s[256];
    int t = threadIdx.x;
    int i = blockIdx.x * 256 + t;
    int v = (i < N_NODES) ? cnt_act[i] : 0;
    s[t] = v;
    __syncthreads();
    for (int off = 1; off < 256; off <<= 1) {
        int u = (t >= off) ? s[t - off] : 0;
        __syncthreads();
        s[t] += u;
        __syncthreads();
    }
    if (i < N_NODES) row_ptr[i] = blockOff[blockIdx.x] + s[t] - v;  // exclusive
}

// ---------------------------------------------------------------------------
// fill: scatter active edge ids into CSR slots (csr_eid lives in d_out).
// ---------------------------------------------------------------------------
__global__ void fill_kernel(const int* __restrict__ src,
                            const int* __restrict__ dst,
                            const int* __restrict__ region,
                            const int* __restrict__ row_ptr,
                            int* __restrict__ cursor,
                            int* __restrict__ csr_eid) {
    int e = blockIdx.x * blockDim.x + threadIdx.x;
    int s = src[e];
    int d = dst[e];
    if (region[s] == region[d]) {
        int pos = row_ptr[d] + atomicAdd(cursor + d, 1);
        csr_eid[pos] = e;
    }
}

// ---------------------------------------------------------------------------
// fused layer (gather, NO atomics): 16 lanes per node, lane j owns channel j.
// ---------------------------------------------------------------------------
template <int IN_C>
__global__ void layer_gather(const float* __restrict__ x,       // pos at n*16+0..1
                             const float* __restrict__ hbase,   // stride 16
                             const int* __restrict__ src,
                             const int* __restrict__ csr_eid,
                             const int* __restrict__ row_ptr,
                             const int* __restrict__ cnt_act,
                             const int* __restrict__ cnt_all,
                             const float* __restrict__ Win,     // (2, IN_C*16)
                             const float* __restrict__ bin,     // (IN_C*16)
                             const float* __restrict__ Wout,    // (16,16)
                             const float* __restrict__ bout,    // (16)
                             float* __restrict__ hout) {
    int t = blockIdx.x * blockDim.x + threadIdx.x;
    int n = t >> 4;                 // node
    int j = t & 15;                 // output channel of the spatial MLP

    float w0[IN_C], w1[IN_C], bb[IN_C];
#pragma unroll
    for (int c = 0; c < IN_C; ++c) {
        w0[c] = Win[c * HID + j];
        w1[c] = Win[IN_C * HID + c * HID + j];
        bb[c] = bin[c * HID + j];
    }

    float px = x[n * 16 + 0];
    float py = x[n * 16 + 1];

    int beg = row_ptr[n];
    int cntA = cnt_act[n];

    float msg = 0.0f;
    for (int k = 0; k < cntA; ++k) {
        int e = csr_eid[beg + k];
        int s = src[e];
        float rx = px - x[s * 16 + 0];     // rel = pos[dst]-pos[src], dst==n
        float ry = py - x[s * 16 + 1];
        const float* hs = hbase + s * 16;
        float m = 0.0f;
#pragma unroll
        for (int c = 0; c < IN_C; ++c) {
            float sp = fmaf(rx, w0[c], fmaf(ry, w1[c], bb[c]));
            sp = fmaxf(sp, 0.0f);
            m = fmaf(hs[c], sp, m);
        }
        msg += m;
    }

    float inv = 1.0f / fmaxf((float)cnt_all[n], 1.0f);
    float a = msg * inv;                    // this lane's a_j

    int lane_base = (threadIdx.x & 63) & 0x30;
    float o = bout[j];
#pragma unroll
    for (int c = 0; c < HID; ++c) {
        float ac = __shfl(a, lane_base + c, 64);
        o = fmaf(ac, Wout[c * HID + j], o);
    }
    hout[n * HID + j] = fmaxf(o, 0.0f);
}

// ---------------------------------------------------------------------------
// decoder: z=[h[src],h[dst]] -> relu(z@Wd1+b1) -> relu(@Wd2+b2) -> sigmoid(@Wd3+b3)
// Runs LAST; overwrites d_out (which held csr_eid).
// ---------------------------------------------------------------------------
__global__ void decoder_kernel(const float* __restrict__ h,
                               const int* __restrict__ src,
                               const int* __restrict__ dst,
                               const float* __restrict__ Wd1,  // (32,16)
                               const float* __restrict__ bd1,
                               const float* __restrict__ Wd2,  // (16,16)
                               const float* __restrict__ bd2,
                               const float* __restrict__ Wd3,  // (16,1)
                               const float* __restrict__ bd3,
                               float* __restrict__ out) {
    int e = blockIdx.x * blockDim.x + threadIdx.x;
    if (e >= N_EDGES) return;
    int s = src[e];
    int d = dst[e];

    float z[32];
    const float4* hs = (const float4*)(h + s * HID);
    const float4* hd = (const float4*)(h + d * HID);
#pragma unroll
    for (int q = 0; q < 4; ++q) {
        float4 v = hs[q];
        z[q * 4 + 0] = v.x; z[q * 4 + 1] = v.y; z[q * 4 + 2] = v.z; z[q * 4 + 3] = v.w;
    }
#pragma unroll
    for (int q = 0; q < 4; ++q) {
        float4 v = hd[q];
        z[16 + q * 4 + 0] = v.x; z[16 + q * 4 + 1] = v.y; z[16 + q * 4 + 2] = v.z; z[16 + q * 4 + 3] = v.w;
    }

    float d1[HID];
#pragma unroll
    for (int j = 0; j < HID; ++j) d1[j] = bd1[j];
#pragma unroll
    for (int c = 0; c < 32; ++c) {
        float zc = z[c];
#pragma unroll
        for (int j = 0; j < HID; ++j) d1[j] = fmaf(zc, Wd1[c * HID + j], d1[j]);
    }
#pragma unroll
    for (int j = 0; j < HID; ++j) d1[j] = fmaxf(d1[j], 0.0f);

    float d2[HID];
#pragma unroll
    for (int j = 0; j < HID; ++j) d2[j] = bd2[j];
#pragma unroll
    for (int c = 0; c < HID; ++c) {
        float dc = d1[c];
#pragma unroll
        for (int j = 0; j < HID; ++j) d2[j] = fmaf(dc, Wd2[c * HID + j], d2[j]);
    }

    float o = bd3[0];
#pragma unroll
    for (int j = 0; j < HID; ++j) o = fmaf(fmaxf(d2[j], 0.0f), Wd3[j], o);

    out[e] = 1.0f / (1.0f + __expf(-o));
}

// ---------------------------------------------------------------------------
extern "C" void kernel_launch(void* const* d_in, const int* in_sizes, int n_in,
                              void* d_out, int out_size, void* d_ws, size_t ws_size,
                              hipStream_t stream) {
    const float* x      = (const float*)d_in[0];
    const int*   edge   = (const int*)d_in[1];   // (2, E): src row then dst row
    const int*   region = (const int*)d_in[2];
    const float* W_in1  = (const float*)d_in[3];
    const float* b_in1  = (const float*)d_in[4];
    const float* W_out1 = (const float*)d_in[5];
    const float* b_out1 = (const float*)d_in[6];
    const float* W_in2  = (const float*)d_in[7];
    const float* b_in2  = (const float*)d_in[8];
    const float* W_out2 = (const float*)d_in[9];
    const float* b_out2 = (const float*)d_in[10];
    const float* W_in3  = (const float*)d_in[11];
    const float* b_in3  = (const float*)d_in[12];
    const float* W_out3 = (const float*)d_in[13];
    const float* b_out3 = (const float*)d_in[14];
    const float* Wd1    = (const float*)d_in[15];
    const float* bd1    = (const float*)d_in[16];
    const float* Wd2    = (const float*)d_in[17];
    const float* bd2    = (const float*)d_in[18];
    const float* Wd3    = (const float*)d_in[19];
    const float* bd3    = (const float*)d_in[20];
    float* out = (float*)d_out;

    const int* src = edge;
    const int* dst = edge + N_EDGES;

    // workspace (~7.2 MB):
    //   hA[800000 f] hB[800000 f] cnt_all[50000 i] cnt_act[50000 i]
    //   row_ptr[50000 i] cursor[50000 i] blockSums[256 i] blockOff[256 i]
    // csr_eid (800000 ints worst case) lives in d_out; decoder overwrites it last.
    float* ws        = (float*)d_ws;
    float* hA        = ws;
    float* hB        = hA + N_NODES * HID;
    int*   cnt_all   = (int*)(hB + N_NODES * HID);
    int*   cnt_act   = cnt_all + N_NODES;
    int*   row_ptr   = cnt_act + N_NODES;
    int*   cursor    = row_ptr + N_NODES;
    int*   blockSums = cursor + N_NODES;
    int*   blockOff  = blockSums + 256;
    int*   csr_eid   = (int*)d_out;

    const int BLK = 256;
    const int egrid = N_EDGES / BLK;          // 3125, exact
    const int lgrid = N_NODES * HID / BLK;    // 3125, exact (16 lanes/node)

    // zero cnt_all + cnt_act + row_ptr + cursor (contiguous 4*50000 ints)
    hipMemsetAsync(cnt_all, 0, (size_t)(4 * N_NODES) * sizeof(int), stream);

    count_kernel<<<egrid, BLK, 0, stream>>>(src, dst, region, cnt_all, cnt_act);
    scanA_kernel<<<SCAN_BLOCKS, 256, 0, stream>>>(cnt_act, blockSums);
    scanB_kernel<<<1, 256, 0, stream>>>(blockSums, blockOff);
    scanC_kernel<<<SCAN_BLOCKS, 256, 0, stream>>>(cnt_act, blockOff, row_ptr);
    fill_kernel<<<egrid, BLK, 0, stream>>>(src, dst, region, row_ptr, cursor, csr_eid);

    // layer 1: h from x columns 2..15 (row stride 16)
    layer_gather<14><<<lgrid, BLK, 0, stream>>>(x, x + 2, src, csr_eid, row_ptr,
                                                cnt_act, cnt_all, W_in1, b_in1,
                                                W_out1, b_out1, hA);
    layer_gather<16><<<lgrid, BLK, 0, stream>>>(x, hA, src, csr_eid, row_ptr,
                                                cnt_act, cnt_all, W_in2, b_in2,
                                                W_out2, b_out2, hB);
    layer_gather<16><<<lgrid, BLK, 0, stream>>>(x, hB, src, csr_eid, row_ptr,
                                                cnt_act, cnt_all, W_in3, b_in3,
                                                W_out3, b_out3, hA);

    decoder_kernel<<<egrid, BLK, 0, stream>>>(hA, src, dst, Wd1, bd1, Wd2, bd2, Wd3, bd3, out);
}